// Round 7
// baseline (506.640 us; speedup 1.0000x reference)
//
#include <hip/hip_runtime.h>
#include <hip/hip_bf16.h>
#include <stdint.h>

typedef __hip_bfloat16 bf16;
typedef __attribute__((ext_vector_type(8))) short short8;   // 8 bf16 = 4 VGPRs (MFMA A/B frag)
typedef __attribute__((ext_vector_type(4))) float floatx4;  // 16x16 MFMA C/D frag

#define AS1(p) ((const __attribute__((address_space(1))) void*)(p))
#define AS3(p) ((__attribute__((address_space(3))) void*)(p))

#define M_DIM 4096
#define H_DIM 1024
#define STAGE 24576          // A 8KB + B 16KB per K-step(32); 3 stages = 72KB -> 2 blocks/CU

// fp32 -> bf16 bits, round-to-nearest-even (inputs are finite)
__device__ __forceinline__ unsigned short f2bf(float f) {
    uint32_t u = __float_as_uint(f);
    uint32_t r = (u + 0x7FFFu + ((u >> 16) & 1u)) >> 16;
    return (unsigned short)r;
}
__device__ __forceinline__ float fast_sigmoid(float v) {
    return 1.0f / (1.0f + __expf(-v));
}
__device__ __forceinline__ float fast_tanh(float v) {
    return 2.0f / (1.0f + __expf(-2.0f * v)) - 1.0f;
}

// ---------------------------------------------------------------------------
// Kernel 1: PACK fp32 -> bf16 1KB chunks in 16x16x32-fragment lane order:
// chunk = [4 kg][16 row][8 bf16]; lane l holds bytes l*16 (row=l&15, kg=l>>4).
// Unified KT in [0,64): KT<32 -> x / Wx (k = KT*32..), KT>=32 -> h / Wh.
// Chunk map (32768 x 1KB = 32MB):
//   A (W<16384):  W = mx*512 + KT*8 + ch      (mx<32: 128-row panel, ch<8:
//                 16-row group); row = mx*128 + ch*16 + (l&15)
//   B (W>=16384): W-16384 = ny*1024 + KT*16 + b   (ny<16: 64-col panel,
//                 b = g*4 + c4: gate g, 16-col group c4);
//                 row = ny*64 + c4*16 + (l&15)
__global__ __launch_bounds__(256)
void pack_bf16(const float* __restrict__ x, const float* __restrict__ h,
               const float* Wxf, const float* Wxi, const float* Wxo, const float* Wxc,
               const float* Whf, const float* Whi, const float* Who, const float* Whc,
               unsigned short* __restrict__ ws)
{
    const int w = threadIdx.x >> 6;
    const int l = threadIdx.x & 63;
    const uint32_t W = blockIdx.x * 4u + (uint32_t)w;   // chunk id [0, 32768)

    const uint32_t kg = (uint32_t)l >> 4;    // k-group of 8
    const uint32_t rr = (uint32_t)l & 15u;   // row/col within fragment

    const float* src;
    uint32_t row, ktl;
    if (W < 16384u) {                    // A-chunks (x / h)
        const uint32_t ch = W & 7u;
        const uint32_t KT = (W >> 3) & 63u;
        const uint32_t mx = W >> 9;
        src = (KT < 32u) ? x : h;
        ktl = KT & 31u;
        row = mx * 128u + ch * 16u + rr;
    } else {                             // B-chunks (Wx_g / Wh_g)
        const uint32_t V  = W - 16384u;
        const uint32_t b  = V & 15u;
        const uint32_t KT = (V >> 4) & 63u;
        const uint32_t ny = V >> 10;
        const uint32_t g  = b >> 2;
        const uint32_t c4 = b & 3u;
        if (KT < 32u)
            src = (g == 0) ? Wxf : (g == 1) ? Wxi : (g == 2) ? Wxo : Wxc;
        else
            src = (g == 0) ? Whf : (g == 1) ? Whi : (g == 2) ? Who : Whc;
        ktl = KT & 31u;
        row = ny * 64u + c4 * 16u + rr;
    }
    const float* s = src + (size_t)row * 1024u + ktl * 32u + kg * 8u;
    const float4 v0 = *(const float4*)s;
    const float4 v1 = *(const float4*)(s + 4);
    short8 pk;
    pk[0] = (short)f2bf(v0.x); pk[1] = (short)f2bf(v0.y);
    pk[2] = (short)f2bf(v0.z); pk[3] = (short)f2bf(v0.w);
    pk[4] = (short)f2bf(v1.x); pk[5] = (short)f2bf(v1.y);
    pk[6] = (short)f2bf(v1.z); pk[7] = (short)f2bf(v1.w);
    *(short8*)(ws + (size_t)W * 512u + (uint32_t)l * 8u) = pk;
}

// ---------------------------------------------------------------------------
// Kernel 2: fused 4-gate GEMM + LSTM pointwise.
// Round-0 skeleton (3-stage LDS ring, 2 blocks/CU, ONE barrier + counted
// vmcnt per K-step, A+B both staged in LDS) with the LDS-read traffic cut:
//  - 4 waves/block in a (2,2) wave grid; wave patch = 64 rows x 32 cols x
//    4 gates.  Per block-K-step LDS reads: 48 KB (vs round-0's 64 KB) --
//    the binding pipe per the round-0/5 accounting.
//  - acc[4][2][4] = 128 AGPR/wave (2 waves/SIMD; 2 blocks x 4 waves = 8/CU).
//  - unified-KT packed source -> pure pointer-increment staging (round-5:
//    VALUBusy 40->24%).
//  - barrier drains lgkmcnt(0) (stage-ring WAR fix) + sched_barrier(0).
#define GLL(srcp, dstp) __builtin_amdgcn_global_load_lds(AS1(srcp), AS3(dstp), 16, 0, 0)
#define WAITB(N) do {                                                          \
    asm volatile("s_waitcnt vmcnt(" #N ") lgkmcnt(0)\ns_barrier" ::: "memory");\
    __builtin_amdgcn_sched_barrier(0);                                         \
} while (0)

#define MFMA16(a, b, c) __builtin_amdgcn_mfma_f32_16x16x32_bf16((a), (b), (c), 0, 0, 0)

#define ISSUE(SL) do {                                                        \
    GLL(p0, lds + (SL)*STAGE + lo0); p0 += ks0;                               \
    GLL(p1, lds + (SL)*STAGE + lo1); p1 += ks1;                               \
    GLL(p2, lds + (SL)*STAGE + lo2); p2 += ks2;                               \
    GLL(p3, lds + (SL)*STAGE + lo3); p3 += ks3;                               \
    GLL(p4, lds + (SL)*STAGE + lo4); p4 += ks4;                               \
    GLL(p5, lds + (SL)*STAGE + lo5); p5 += ks5;                               \
} while (0)

#define QUAD(G, CC, BF)                                                       \
    acc[G][CC][0] = MFMA16(a0_, BF, acc[G][CC][0]);                           \
    acc[G][CC][1] = MFMA16(a1_, BF, acc[G][CC][1]);                           \
    acc[G][CC][2] = MFMA16(a2_, BF, acc[G][CC][2]);                           \
    acc[G][CC][3] = MFMA16(a3_, BF, acc[G][CC][3]);

#define COMPUTE(SC) do {                                                      \
    const short8 a0_ = *(const short8*)(ldsA + (SC)*STAGE + 0);               \
    const short8 a1_ = *(const short8*)(ldsA + (SC)*STAGE + 1024);            \
    const short8 a2_ = *(const short8*)(ldsA + (SC)*STAGE + 2048);            \
    const short8 a3_ = *(const short8*)(ldsA + (SC)*STAGE + 3072);            \
    const short8 b00_ = *(const short8*)(ldsB + (SC)*STAGE + 0);              \
    const short8 b01_ = *(const short8*)(ldsB + (SC)*STAGE + 1024);           \
    const short8 b10_ = *(const short8*)(ldsB + (SC)*STAGE + 4096);           \
    const short8 b11_ = *(const short8*)(ldsB + (SC)*STAGE + 4096 + 1024);    \
    const short8 b20_ = *(const short8*)(ldsB + (SC)*STAGE + 8192);           \
    const short8 b21_ = *(const short8*)(ldsB + (SC)*STAGE + 8192 + 1024);    \
    const short8 b30_ = *(const short8*)(ldsB + (SC)*STAGE + 12288);          \
    const short8 b31_ = *(const short8*)(ldsB + (SC)*STAGE + 12288 + 1024);   \
    QUAD(0, 0, b00_) QUAD(0, 1, b01_)                                         \
    QUAD(1, 0, b10_) QUAD(1, 1, b11_)                                         \
    QUAD(2, 0, b20_) QUAD(2, 1, b21_)                                         \
    QUAD(3, 0, b30_) QUAD(3, 1, b31_)                                         \
} while (0)

#define ITER(SC, SL) do { WAITB(6); ISSUE(SL); COMPUTE(SC); } while (0)

__global__ __launch_bounds__(256, 2)
void lstm_fused_kernel(const unsigned short* __restrict__ ws,
                       const float* __restrict__ c,
                       const float* __restrict__ bxf, const float* __restrict__ bhf,
                       const float* __restrict__ bxi, const float* __restrict__ bhi,
                       const float* __restrict__ bxo, const float* __restrict__ bho,
                       const float* __restrict__ bxc, const float* __restrict__ bhc,
                       float* __restrict__ out)
{
    __shared__ __align__(16) char lds[3 * STAGE];   // 72 KB

    const int tid  = threadIdx.x;
    const int w    = tid >> 6;     // 0..3
    const int lane = tid & 63;

    // XCD-aware block swizzle (proven in round-0): grid 512 = 32 mx x 16 ny
    const int bid = blockIdx.x;
    const int mx  = bid >> 4;                              // [0,32)
    const int ny  = ((bid & 7) << 1) | ((bid >> 3) & 1);   // [0,16)
    const int bm0 = mx * 128;
    const int bn0 = ny * 64;

    const int wM = w >> 1;         // 64-row half
    const int wc = w & 1;          // 32-col half (2 c4-groups of 16)

    // staging: 24 chunks/stage; wave w DMAs ch = w*6 + i, i<6.
    // ch<8: A chunk ch; ch>=8: B chunk b = ch-8 (= g*4+c4).
    // LDS stage layout: A at ch*1024 ([0,8K)), B at 8192 + b*1024 -- i.e.
    // loff = ch*1024 uniformly.
    const unsigned short* p0; const unsigned short* p1; const unsigned short* p2;
    const unsigned short* p3; const unsigned short* p4; const unsigned short* p5;
    uint32_t lo0, lo1, lo2, lo3, lo4, lo5, ks0, ks1, ks2, ks3, ks4, ks5;
#define CHDEC(CH, P, LO, KS) do {                                             \
    const uint32_t ch_ = (uint32_t)(CH);                                      \
    if (ch_ < 8u) {                                                           \
        P  = ws + ((uint32_t)mx * 512u + ch_) * 512u + (uint32_t)lane * 8u;   \
        KS = 8u * 512u;                                                       \
    } else {                                                                  \
        const uint32_t b_ = ch_ - 8u;                                         \
        P  = ws + (16384u + (uint32_t)ny * 1024u + b_) * 512u                 \
                + (uint32_t)lane * 8u;                                        \
        KS = 16u * 512u;                                                      \
    }                                                                         \
    LO = ch_ * 1024u;                                                         \
} while (0)
    CHDEC(w * 6 + 0, p0, lo0, ks0);
    CHDEC(w * 6 + 1, p1, lo1, ks1);
    CHDEC(w * 6 + 2, p2, lo2, ks2);
    CHDEC(w * 6 + 3, p3, lo3, ks3);
    CHDEC(w * 6 + 4, p4, lo4, ks4);
    CHDEC(w * 6 + 5, p5, lo5, ks5);
#undef CHDEC

    // fragment base pointers; all LDS reads are base + immediate offset.
    // A frags: chunk wM*4 + mt.  B frags: chunk b = g*4 + wc*2 + cc.
    const char* ldsA = lds + (uint32_t)lane * 16u + (uint32_t)wM * 4096u;
    const char* ldsB = lds + (uint32_t)lane * 16u + 8192u + (uint32_t)wc * 2048u;

    floatx4 acc[4][2][4];   // [gate][c-group][m-tile] = 128 fp32/lane
#pragma unroll
    for (int g = 0; g < 4; ++g)
#pragma unroll
        for (int cc = 0; cc < 2; ++cc)
#pragma unroll
            for (int mt = 0; mt < 4; ++mt)
                acc[g][cc][mt] = (floatx4){0.f, 0.f, 0.f, 0.f};

    // prologue: stages 0,1 in flight (12 outstanding/wave)
    ISSUE(0);
    ISSUE(1);

    // 64 K-steps; ITER(kt) computes stage kt%3, issues kt+2 -> (kt+2)%3.
    for (int t = 0; t < 20; ++t) {
        ITER(0, 2); ITER(1, 0); ITER(2, 1);     // kt = 3t, 3t+1, 3t+2
    }
    ITER(0, 2);                                 // kt = 60
    ITER(1, 0);                                 // kt = 61 (issues loads(63))
    WAITB(6); COMPUTE(2);                       // kt = 62
    WAITB(0); COMPUTE(0);                       // kt = 63

    // ------------------------------------------------------------------ epi
    // All 4 gates wave-local.  C/D: col = lane&15, row = (lane>>4)*4 + reg
    const int lrc   = lane & 15;
    const int lquad = lane >> 4;
    const int wrow  = wM * 64;
    float* out_ct = out;
    float* out_ht = out + (size_t)M_DIM * H_DIM;

#pragma unroll
    for (int cc = 0; cc < 2; ++cc) {
        const int colg = bn0 + wc * 32 + cc * 16 + lrc;
        const float bf_ = bxf[colg] + bhf[colg];
        const float bi_ = bxi[colg] + bhi[colg];
        const float bo_ = bxo[colg] + bho[colg];
        const float bc_ = bxc[colg] + bhc[colg];
#pragma unroll
        for (int mt = 0; mt < 4; ++mt) {
#pragma unroll
            for (int r = 0; r < 4; ++r) {
                const int row = bm0 + wrow + mt * 16 + lquad * 4 + r;
                const float f    = fast_sigmoid(acc[0][cc][mt][r] + bf_);
                const float ii   = fast_sigmoid(acc[1][cc][mt][r] + bi_);
                const float o    = fast_sigmoid(acc[2][cc][mt][r] + bo_);
                const float ctil = fast_tanh(acc[3][cc][mt][r] + bc_);
                const float cv   = c[(size_t)row * H_DIM + colg];
                const float ctn  = f * cv + ctil * ii;
                const float htn  = fast_tanh(ctn) * o;
                out_ct[(size_t)row * H_DIM + colg] = ctn;
                out_ht[(size_t)row * H_DIM + colg] = htn;
            }
        }
    }
}

extern "C" void kernel_launch(void* const* d_in, const int* in_sizes, int n_in,
                              void* d_out, int out_size, void* d_ws, size_t ws_size,
                              hipStream_t stream) {
    (void)in_sizes; (void)n_in; (void)out_size; (void)ws_size;
    const float* x   = (const float*)d_in[0];
    const float* c   = (const float*)d_in[1];
    const float* h   = (const float*)d_in[2];
    const float* Wxf = (const float*)d_in[3];  const float* bxf = (const float*)d_in[4];
    const float* Whf = (const float*)d_in[5];  const float* bhf = (const float*)d_in[6];
    const float* Wxi = (const float*)d_in[7];  const float* bxi = (const float*)d_in[8];
    const float* Whi = (const float*)d_in[9];  const float* bhi = (const float*)d_in[10];
    const float* Wxo = (const float*)d_in[11]; const float* bxo = (const float*)d_in[12];
    const float* Who = (const float*)d_in[13]; const float* bho = (const float*)d_in[14];
    const float* Wxc = (const float*)d_in[15]; const float* bxc = (const float*)d_in[16];
    const float* Whc = (const float*)d_in[17]; const float* bhc = (const float*)d_in[18];
    float* out = (float*)d_out;
    unsigned short* ws = (unsigned short*)d_ws;   // 32768 chunks x 1 KB = 32 MB

    pack_bf16<<<8192, 256, 0, stream>>>(x, h,
        Wxf, Wxi, Wxo, Wxc, Whf, Whi, Who, Whc, ws);

    lstm_fused_kernel<<<512, 256, 0, stream>>>(ws, c,
        bxf, bhf, bxi, bhi, bxo, bho, bxc, bhc, out);
}

// Round 8
// 477.736 us; speedup vs baseline: 1.0605x; 1.0605x over previous
//
#include <hip/hip_runtime.h>
#include <hip/hip_bf16.h>
#include <stdint.h>

typedef __hip_bfloat16 bf16;
typedef __attribute__((ext_vector_type(8))) short short8;   // 8 bf16 = 4 VGPRs (MFMA A/B frag)
typedef __attribute__((ext_vector_type(4))) float floatx4;  // 16x16 MFMA C/D frag

#define AS1(p) ((const __attribute__((address_space(1))) void*)(p))
#define AS3(p) ((__attribute__((address_space(3))) void*)(p))

#define M_DIM 4096
#define H_DIM 1024
#define STAGE 24576          // A 8KB + B 16KB per K-step(32); 3 stages = 72KB -> 2 blocks/CU

// fp32 -> bf16 bits, round-to-nearest-even (inputs are finite)
__device__ __forceinline__ unsigned short f2bf(float f) {
    uint32_t u = __float_as_uint(f);
    uint32_t r = (u + 0x7FFFu + ((u >> 16) & 1u)) >> 16;
    return (unsigned short)r;
}
__device__ __forceinline__ float fast_sigmoid(float v) {
    return 1.0f / (1.0f + __expf(-v));
}
__device__ __forceinline__ float fast_tanh(float v) {
    return 2.0f / (1.0f + __expf(-2.0f * v)) - 1.0f;
}

// ---------------------------------------------------------------------------
// Kernel 1: PACK fp32 -> bf16 1KB chunks in 16x16x32-fragment lane order:
// chunk = [4 kg][16 row][8 bf16]; lane l holds bytes l*16 (row=l&15, kg=l>>4).
// Unified KT in [0,64): KT<32 -> x / Wx (k = KT*32..), KT>=32 -> h / Wh.
// Chunk map (32768 x 1KB = 32MB):
//   A (W<16384):  W = mx*512 + KT*8 + ch      (mx<32: 128-row panel, ch<8:
//                 16-row group); row = mx*128 + ch*16 + (l&15)
//   B (W>=16384): W-16384 = ny*1024 + KT*16 + b   (ny<16: 64-col panel,
//                 b = g*4 + c4: gate g, 16-col group c4);
//                 row = ny*64 + c4*16 + (l&15)
__global__ __launch_bounds__(256)
void pack_bf16(const float* __restrict__ x, const float* __restrict__ h,
               const float* Wxf, const float* Wxi, const float* Wxo, const float* Wxc,
               const float* Whf, const float* Whi, const float* Who, const float* Whc,
               unsigned short* __restrict__ ws)
{
    const int w = threadIdx.x >> 6;
    const int l = threadIdx.x & 63;
    const uint32_t W = blockIdx.x * 4u + (uint32_t)w;   // chunk id [0, 32768)

    const uint32_t kg = (uint32_t)l >> 4;    // k-group of 8
    const uint32_t rr = (uint32_t)l & 15u;   // row/col within fragment

    const float* src;
    uint32_t row, ktl;
    if (W < 16384u) {                    // A-chunks (x / h)
        const uint32_t ch = W & 7u;
        const uint32_t KT = (W >> 3) & 63u;
        const uint32_t mx = W >> 9;
        src = (KT < 32u) ? x : h;
        ktl = KT & 31u;
        row = mx * 128u + ch * 16u + rr;
    } else {                             // B-chunks (Wx_g / Wh_g)
        const uint32_t V  = W - 16384u;
        const uint32_t b  = V & 15u;
        const uint32_t KT = (V >> 4) & 63u;
        const uint32_t ny = V >> 10;
        const uint32_t g  = b >> 2;
        const uint32_t c4 = b & 3u;
        if (KT < 32u)
            src = (g == 0) ? Wxf : (g == 1) ? Wxi : (g == 2) ? Wxo : Wxc;
        else
            src = (g == 0) ? Whf : (g == 1) ? Whi : (g == 2) ? Who : Whc;
        ktl = KT & 31u;
        row = ny * 64u + c4 * 16u + rr;
    }
    const float* s = src + (size_t)row * 1024u + ktl * 32u + kg * 8u;
    const float4 v0 = *(const float4*)s;
    const float4 v1 = *(const float4*)(s + 4);
    short8 pk;
    pk[0] = (short)f2bf(v0.x); pk[1] = (short)f2bf(v0.y);
    pk[2] = (short)f2bf(v0.z); pk[3] = (short)f2bf(v0.w);
    pk[4] = (short)f2bf(v1.x); pk[5] = (short)f2bf(v1.y);
    pk[6] = (short)f2bf(v1.z); pk[7] = (short)f2bf(v1.w);
    *(short8*)(ws + (size_t)W * 512u + (uint32_t)l * 8u) = pk;
}

// ---------------------------------------------------------------------------
// Kernel 2: fused 4-gate GEMM + LSTM pointwise.  Round-7 geometry (the
// LDS-traffic minimum: 4 waves, wave = 64r x 32c x 4 gates, block tile
// 128 x 64c x 4g, 144 KB LDS bytes per CU-block-step vs round-0's 176)
// with SPILL-PROOF codegen:
//  - acc = 32 NAMED floatx4 vars (round-7's acc[4][2][4] array was never
//    SROA-promoted -> every "memory"-clobber barrier spilled it: 1.16 GB
//    scratch writes.  Named scalars cannot live in a stack slot.)
//  - COMPUTE loads A frags once, B frags one-at-a-time (live range 4 MFMAs).
//  - unified-KT pointer-increment staging; lgkm-safe barrier; sched fence.
#define GLL(srcp, dstp) __builtin_amdgcn_global_load_lds(AS1(srcp), AS3(dstp), 16, 0, 0)
#define WAITB(N) do {                                                          \
    asm volatile("s_waitcnt vmcnt(" #N ") lgkmcnt(0)\ns_barrier" ::: "memory");\
    __builtin_amdgcn_sched_barrier(0);                                         \
} while (0)

#define MFMA16(a, b, c) __builtin_amdgcn_mfma_f32_16x16x32_bf16((a), (b), (c), 0, 0, 0)

#define ISSUE(SL) do {                                                        \
    GLL(p0, lds + (SL)*STAGE + lo0); p0 += ks0;                               \
    GLL(p1, lds + (SL)*STAGE + lo1); p1 += ks1;                               \
    GLL(p2, lds + (SL)*STAGE + lo2); p2 += ks2;                               \
    GLL(p3, lds + (SL)*STAGE + lo3); p3 += ks3;                               \
    GLL(p4, lds + (SL)*STAGE + lo4); p4 += ks4;                               \
    GLL(p5, lds + (SL)*STAGE + lo5); p5 += ks5;                               \
} while (0)

// B frag for (gate G, col-group CC) lives only across its 4 MFMAs
#define GEMM_GC(SC, G, CC) do {                                               \
    const short8 bf_ = *(const short8*)(ldsB + (SC)*STAGE                     \
                                        + (G)*4096 + (CC)*1024);              \
    acc_##G##_##CC##_0 = MFMA16(a0_, bf_, acc_##G##_##CC##_0);                \
    acc_##G##_##CC##_1 = MFMA16(a1_, bf_, acc_##G##_##CC##_1);                \
    acc_##G##_##CC##_2 = MFMA16(a2_, bf_, acc_##G##_##CC##_2);                \
    acc_##G##_##CC##_3 = MFMA16(a3_, bf_, acc_##G##_##CC##_3);                \
} while (0)

#define COMPUTE(SC) do {                                                      \
    const short8 a0_ = *(const short8*)(ldsA + (SC)*STAGE + 0);               \
    const short8 a1_ = *(const short8*)(ldsA + (SC)*STAGE + 1024);            \
    const short8 a2_ = *(const short8*)(ldsA + (SC)*STAGE + 2048);            \
    const short8 a3_ = *(const short8*)(ldsA + (SC)*STAGE + 3072);            \
    GEMM_GC(SC, 0, 0); GEMM_GC(SC, 0, 1);                                     \
    GEMM_GC(SC, 1, 0); GEMM_GC(SC, 1, 1);                                     \
    GEMM_GC(SC, 2, 0); GEMM_GC(SC, 2, 1);                                     \
    GEMM_GC(SC, 3, 0); GEMM_GC(SC, 3, 1);                                     \
} while (0)

#define ITER(SC, SL) do { WAITB(6); ISSUE(SL); COMPUTE(SC); } while (0)

__global__ __launch_bounds__(256, 2)
void lstm_fused_kernel(const unsigned short* __restrict__ ws,
                       const float* __restrict__ c,
                       const float* __restrict__ bxf, const float* __restrict__ bhf,
                       const float* __restrict__ bxi, const float* __restrict__ bhi,
                       const float* __restrict__ bxo, const float* __restrict__ bho,
                       const float* __restrict__ bxc, const float* __restrict__ bhc,
                       float* __restrict__ out)
{
    __shared__ __align__(16) char lds[3 * STAGE];   // 72 KB

    const int tid  = threadIdx.x;
    const int w    = tid >> 6;     // 0..3
    const int lane = tid & 63;

    // XCD-aware block swizzle: grid 512 = 32 mx x 16 ny
    const int bid = blockIdx.x;
    const int mx  = bid >> 4;                              // [0,32)
    const int ny  = ((bid & 7) << 1) | ((bid >> 3) & 1);   // [0,16)
    const int bm0 = mx * 128;
    const int bn0 = ny * 64;

    const int wM = w >> 1;         // 64-row half
    const int wc = w & 1;          // 32-col half (2 c4-groups of 16)

    // staging: 24 chunks/stage; wave w DMAs ch = w*6 + i, i<6.
    // ch<8: A chunk ch; ch>=8: B chunk b = ch-8 (= g*4+c4).
    // LDS stage layout: loff = ch*1024 uniformly (A [0,8K), B 8K+b*1024).
    const unsigned short* p0; const unsigned short* p1; const unsigned short* p2;
    const unsigned short* p3; const unsigned short* p4; const unsigned short* p5;
    uint32_t lo0, lo1, lo2, lo3, lo4, lo5, ks0, ks1, ks2, ks3, ks4, ks5;
#define CHDEC(CH, P, LO, KS) do {                                             \
    const uint32_t ch_ = (uint32_t)(CH);                                      \
    if (ch_ < 8u) {                                                           \
        P  = ws + ((uint32_t)mx * 512u + ch_) * 512u + (uint32_t)lane * 8u;   \
        KS = 8u * 512u;                                                       \
    } else {                                                                  \
        const uint32_t b_ = ch_ - 8u;                                         \
        P  = ws + (16384u + (uint32_t)ny * 1024u + b_) * 512u                 \
                + (uint32_t)lane * 8u;                                        \
        KS = 16u * 512u;                                                      \
    }                                                                         \
    LO = ch_ * 1024u;                                                         \
} while (0)
    CHDEC(w * 6 + 0, p0, lo0, ks0);
    CHDEC(w * 6 + 1, p1, lo1, ks1);
    CHDEC(w * 6 + 2, p2, lo2, ks2);
    CHDEC(w * 6 + 3, p3, lo3, ks3);
    CHDEC(w * 6 + 4, p4, lo4, ks4);
    CHDEC(w * 6 + 5, p5, lo5, ks5);
#undef CHDEC

    // fragment base pointers; all LDS reads are base + immediate offset.
    // A frags: chunk wM*4 + mt.  B frags: chunk b = g*4 + wc*2 + cc.
    const char* ldsA = lds + (uint32_t)lane * 16u + (uint32_t)wM * 4096u;
    const char* ldsB = lds + (uint32_t)lane * 16u + 8192u + (uint32_t)wc * 2048u;

    // 32 named accumulators (g, cc, mt) -- SROA-proof
#define DECL_ACC(G, CC)                                                       \
    floatx4 acc_##G##_##CC##_0 = {0.f,0.f,0.f,0.f};                           \
    floatx4 acc_##G##_##CC##_1 = {0.f,0.f,0.f,0.f};                           \
    floatx4 acc_##G##_##CC##_2 = {0.f,0.f,0.f,0.f};                           \
    floatx4 acc_##G##_##CC##_3 = {0.f,0.f,0.f,0.f};
    DECL_ACC(0, 0) DECL_ACC(0, 1)
    DECL_ACC(1, 0) DECL_ACC(1, 1)
    DECL_ACC(2, 0) DECL_ACC(2, 1)
    DECL_ACC(3, 0) DECL_ACC(3, 1)
#undef DECL_ACC

    // prologue: stages 0,1 in flight (12 outstanding/wave)
    ISSUE(0);
    ISSUE(1);

    // 64 K-steps; ITER(kt) computes stage kt%3, issues kt+2 -> (kt+2)%3.
    for (int t = 0; t < 20; ++t) {
        ITER(0, 2); ITER(1, 0); ITER(2, 1);     // kt = 3t, 3t+1, 3t+2
    }
    ITER(0, 2);                                 // kt = 60
    ITER(1, 0);                                 // kt = 61 (issues loads(63))
    WAITB(6); COMPUTE(2);                       // kt = 62
    WAITB(0); COMPUTE(0);                       // kt = 63

    // ------------------------------------------------------------------ epi
    // All 4 gates wave-local.  C/D: col = lane&15, row = (lane>>4)*4 + reg
    const int lrc   = lane & 15;
    const int lquad = lane >> 4;
    const int wrow  = wM * 64;
    float* out_ct = out;
    float* out_ht = out + (size_t)M_DIM * H_DIM;

#define EPI_MT(CC, MT) do {                                                   \
    _Pragma("unroll")                                                         \
    for (int r = 0; r < 4; ++r) {                                             \
        const int row = bm0 + wrow + (MT) * 16 + lquad * 4 + r;               \
        const float f    = fast_sigmoid(acc_0_##CC##_##MT[r] + bf_);          \
        const float ii   = fast_sigmoid(acc_1_##CC##_##MT[r] + bi_);          \
        const float o    = fast_sigmoid(acc_2_##CC##_##MT[r] + bo_);          \
        const float ctil = fast_tanh(acc_3_##CC##_##MT[r] + bc_);             \
        const float cv   = c[(size_t)row * H_DIM + colg];                     \
        const float ctn  = f * cv + ctil * ii;                                \
        const float htn  = fast_tanh(ctn) * o;                                \
        out_ct[(size_t)row * H_DIM + colg] = ctn;                             \
        out_ht[(size_t)row * H_DIM + colg] = htn;                             \
    }                                                                         \
} while (0)

#define EPI_CC(CC) do {                                                       \
    const int colg = bn0 + wc * 32 + (CC) * 16 + lrc;                         \
    const float bf_ = bxf[colg] + bhf[colg];                                  \
    const float bi_ = bxi[colg] + bhi[colg];                                  \
    const float bo_ = bxo[colg] + bho[colg];                                  \
    const float bc_ = bxc[colg] + bhc[colg];                                  \
    EPI_MT(CC, 0); EPI_MT(CC, 1); EPI_MT(CC, 2); EPI_MT(CC, 3);               \
} while (0)

    EPI_CC(0);
    EPI_CC(1);
#undef EPI_CC
#undef EPI_MT
}

extern "C" void kernel_launch(void* const* d_in, const int* in_sizes, int n_in,
                              void* d_out, int out_size, void* d_ws, size_t ws_size,
                              hipStream_t stream) {
    (void)in_sizes; (void)n_in; (void)out_size; (void)ws_size;
    const float* x   = (const float*)d_in[0];
    const float* c   = (const float*)d_in[1];
    const float* h   = (const float*)d_in[2];
    const float* Wxf = (const float*)d_in[3];  const float* bxf = (const float*)d_in[4];
    const float* Whf = (const float*)d_in[5];  const float* bhf = (const float*)d_in[6];
    const float* Wxi = (const float*)d_in[7];  const float* bxi = (const float*)d_in[8];
    const float* Whi = (const float*)d_in[9];  const float* bhi = (const float*)d_in[10];
    const float* Wxo = (const float*)d_in[11]; const float* bxo = (const float*)d_in[12];
    const float* Who = (const float*)d_in[13]; const float* bho = (const float*)d_in[14];
    const float* Wxc = (const float*)d_in[15]; const float* bxc = (const float*)d_in[16];
    const float* Whc = (const float*)d_in[17]; const float* bhc = (const float*)d_in[18];
    float* out = (float*)d_out;
    unsigned short* ws = (unsigned short*)d_ws;   // 32768 chunks x 1 KB = 32 MB

    pack_bf16<<<8192, 256, 0, stream>>>(x, h,
        Wxf, Wxi, Wxo, Wxc, Whf, Whi, Who, Whc, ws);

    lstm_fused_kernel<<<512, 256, 0, stream>>>(ws, c,
        bxf, bhf, bxi, bhi, bxo, bho, bxc, bhc, out);
}

// Round 9
// 209.511 us; speedup vs baseline: 2.4182x; 2.2802x over previous
//
#include <hip/hip_runtime.h>
#include <hip/hip_bf16.h>
#include <stdint.h>

typedef __hip_bfloat16 bf16;
typedef __attribute__((ext_vector_type(8))) short short8;   // 8 bf16 = 4 VGPRs (MFMA A/B frag)
typedef __attribute__((ext_vector_type(4))) float floatx4;  // 16x16 MFMA C/D frag

#define AS1(p) ((const __attribute__((address_space(1))) void*)(p))
#define AS3(p) ((__attribute__((address_space(3))) void*)(p))

#define M_DIM 4096
#define H_DIM 1024
#define STAGE 24576          // A 8KB + B 16KB per K-step(32); 3 stages = 72KB -> 2 blocks/CU

// fp32 -> bf16 bits, round-to-nearest-even (inputs are finite)
__device__ __forceinline__ unsigned short f2bf(float f) {
    uint32_t u = __float_as_uint(f);
    uint32_t r = (u + 0x7FFFu + ((u >> 16) & 1u)) >> 16;
    return (unsigned short)r;
}
__device__ __forceinline__ float fast_sigmoid(float v) {
    return 1.0f / (1.0f + __expf(-v));
}
__device__ __forceinline__ float fast_tanh(float v) {
    return 2.0f / (1.0f + __expf(-2.0f * v)) - 1.0f;
}

// ---------------------------------------------------------------------------
// Kernel 1: PACK fp32 -> bf16 1KB chunks in 16x16x32-fragment lane order:
// chunk = [4 kg][16 row][8 bf16]; lane l holds bytes l*16 (row=l&15, kg=l>>4).
// Unified KT in [0,64): KT<32 -> x / Wx (k = KT*32..), KT>=32 -> h / Wh.
// Chunk map (32768 x 1KB = 32MB):
//   A (W<16384):  W = mx*512 + KT*8 + ch      (mx<32: 128-row panel, ch<8:
//                 16-row group); row = mx*128 + ch*16 + (l&15)
//   B (W>=16384): W-16384 = ny*1024 + KT*16 + b   (ny<16: 64-col panel,
//                 b = g*4 + c4: gate g, 16-col group c4);
//                 row = ny*64 + c4*16 + (l&15)
// (This pack + chunk map is absmax-validated by rounds 7/8.)
__global__ __launch_bounds__(256)
void pack_bf16(const float* __restrict__ x, const float* __restrict__ h,
               const float* Wxf, const float* Wxi, const float* Wxo, const float* Wxc,
               const float* Whf, const float* Whi, const float* Who, const float* Whc,
               unsigned short* __restrict__ ws)
{
    const int w = threadIdx.x >> 6;
    const int l = threadIdx.x & 63;
    const uint32_t W = blockIdx.x * 4u + (uint32_t)w;   // chunk id [0, 32768)

    const uint32_t kg = (uint32_t)l >> 4;    // k-group of 8
    const uint32_t rr = (uint32_t)l & 15u;   // row/col within fragment

    const float* src;
    uint32_t row, ktl;
    if (W < 16384u) {                    // A-chunks (x / h)
        const uint32_t ch = W & 7u;
        const uint32_t KT = (W >> 3) & 63u;
        const uint32_t mx = W >> 9;
        src = (KT < 32u) ? x : h;
        ktl = KT & 31u;
        row = mx * 128u + ch * 16u + rr;
    } else {                             // B-chunks (Wx_g / Wh_g)
        const uint32_t V  = W - 16384u;
        const uint32_t b  = V & 15u;
        const uint32_t KT = (V >> 4) & 63u;
        const uint32_t ny = V >> 10;
        const uint32_t g  = b >> 2;
        const uint32_t c4 = b & 3u;
        if (KT < 32u)
            src = (g == 0) ? Wxf : (g == 1) ? Wxi : (g == 2) ? Wxo : Wxc;
        else
            src = (g == 0) ? Whf : (g == 1) ? Whi : (g == 2) ? Who : Whc;
        ktl = KT & 31u;
        row = ny * 64u + c4 * 16u + rr;
    }
    const float* s = src + (size_t)row * 1024u + ktl * 32u + kg * 8u;
    const float4 v0 = *(const float4*)s;
    const float4 v1 = *(const float4*)(s + 4);
    short8 pk;
    pk[0] = (short)f2bf(v0.x); pk[1] = (short)f2bf(v0.y);
    pk[2] = (short)f2bf(v0.z); pk[3] = (short)f2bf(v0.w);
    pk[4] = (short)f2bf(v1.x); pk[5] = (short)f2bf(v1.y);
    pk[6] = (short)f2bf(v1.z); pk[7] = (short)f2bf(v1.w);
    *(short8*)(ws + (size_t)W * 512u + (uint32_t)l * 8u) = pk;
}

// ---------------------------------------------------------------------------
// Kernel 2: fused 4-gate GEMM + LSTM pointwise.
// ROUND-0 GEOMETRY (the acc=64 traffic optimum: 8 waves, wave = 64r x 16c x
// 4 gates, block tile 128r x 64c x 4g; 88 KB LDS bytes/block-step) with the
// two proven improvements:
//  - unified-KT packed source -> staging is pure pointer increments
//    (round-5: VALUBusy 40.5 -> ~24%); all ds_reads base+immediate.
//  - barrier drains lgkmcnt(0) (stage-ring WAR tripwire fix, validated at
//    512 threads in round-5) + sched_barrier(0) fence.
// acc[4][4] = 64 fp32/lane (round-0-proven spill-free; VGPR ~64).
#define GLL(srcp, dstp) __builtin_amdgcn_global_load_lds(AS1(srcp), AS3(dstp), 16, 0, 0)
#define WAITB(N) do {                                                          \
    asm volatile("s_waitcnt vmcnt(" #N ") lgkmcnt(0)\ns_barrier" ::: "memory");\
    __builtin_amdgcn_sched_barrier(0);                                         \
} while (0)

#define MFMA16(a, b, c) __builtin_amdgcn_mfma_f32_16x16x32_bf16((a), (b), (c), 0, 0, 0)

#define ISSUE(SL) do {                                                        \
    GLL(p0, lds + (SL)*STAGE + lo0); p0 += ks0;                               \
    GLL(p1, lds + (SL)*STAGE + lo1); p1 += ks1;                               \
    GLL(p2, lds + (SL)*STAGE + lo2); p2 += ks2;                               \
} while (0)

#define COMPUTE(SC) do {                                                      \
    const short8 a0_ = *(const short8*)(ldsA + (SC)*STAGE + 0);               \
    const short8 a1_ = *(const short8*)(ldsA + (SC)*STAGE + 1024);            \
    const short8 a2_ = *(const short8*)(ldsA + (SC)*STAGE + 2048);            \
    const short8 a3_ = *(const short8*)(ldsA + (SC)*STAGE + 3072);            \
    _Pragma("unroll")                                                         \
    for (int g = 0; g < 4; ++g) {                                             \
        const short8 bf_ = *(const short8*)(ldsB + (SC)*STAGE + g * 4096);    \
        acc[g][0] = MFMA16(a0_, bf_, acc[g][0]);                              \
        acc[g][1] = MFMA16(a1_, bf_, acc[g][1]);                              \
        acc[g][2] = MFMA16(a2_, bf_, acc[g][2]);                              \
        acc[g][3] = MFMA16(a3_, bf_, acc[g][3]);                              \
    }                                                                         \
} while (0)

#define ITER(SC, SL) do { WAITB(3); ISSUE(SL); COMPUTE(SC); } while (0)

__global__ __launch_bounds__(512, 4)
void lstm_fused_kernel(const unsigned short* __restrict__ ws,
                       const float* __restrict__ c,
                       const float* __restrict__ bxf, const float* __restrict__ bhf,
                       const float* __restrict__ bxi, const float* __restrict__ bhi,
                       const float* __restrict__ bxo, const float* __restrict__ bho,
                       const float* __restrict__ bxc, const float* __restrict__ bhc,
                       float* __restrict__ out)
{
    __shared__ __align__(16) char lds[3 * STAGE];   // 72 KB

    const int tid  = threadIdx.x;
    const int w    = tid >> 6;     // 0..7
    const int lane = tid & 63;

    // XCD-aware block swizzle: grid 512 = 32 mx x 16 ny
    const int bid = blockIdx.x;
    const int mx  = bid >> 4;                              // [0,32)
    const int ny  = ((bid & 7) << 1) | ((bid >> 3) & 1);   // [0,16)
    const int bm0 = mx * 128;
    const int bn0 = ny * 64;

    const int wM  = w & 1;         // 64-row half
    const int wcg = w >> 1;        // 16-col group within each gate [0,4)

    // staging: 24 chunks/stage; wave w DMAs ch = w*3 + i, i<3.
    // ch<8: A chunk ch; ch>=8: B chunk b = ch-8 (= g*4+c4).
    // LDS stage layout: loff = ch*1024 uniformly (A [0,8K), B 8K + b*1024).
    const unsigned short* p0; const unsigned short* p1; const unsigned short* p2;
    uint32_t lo0, lo1, lo2, ks0, ks1, ks2;
#define CHDEC(CH, P, LO, KS) do {                                             \
    const uint32_t ch_ = (uint32_t)(CH);                                      \
    if (ch_ < 8u) {                                                           \
        P  = ws + ((uint32_t)mx * 512u + ch_) * 512u + (uint32_t)lane * 8u;   \
        KS = 8u * 512u;                                                       \
    } else {                                                                  \
        const uint32_t b_ = ch_ - 8u;                                         \
        P  = ws + (16384u + (uint32_t)ny * 1024u + b_) * 512u                 \
                + (uint32_t)lane * 8u;                                        \
        KS = 16u * 512u;                                                      \
    }                                                                         \
    LO = ch_ * 1024u;                                                         \
} while (0)
    CHDEC(w * 3 + 0, p0, lo0, ks0);
    CHDEC(w * 3 + 1, p1, lo1, ks1);
    CHDEC(w * 3 + 2, p2, lo2, ks2);
#undef CHDEC

    // fragment base pointers; all LDS reads are base + immediate offset.
    // A frags: chunk wM*4 + mt.  B frags: chunk b = g*4 + wcg.
    const char* ldsA = lds + (uint32_t)lane * 16u + (uint32_t)wM * 4096u;
    const char* ldsB = lds + (uint32_t)lane * 16u + 8192u + (uint32_t)wcg * 1024u;

    floatx4 acc[4][4];   // [gate][m-tile] = 64 fp32/lane (round-0-proven size)
#pragma unroll
    for (int g = 0; g < 4; ++g)
#pragma unroll
        for (int mt = 0; mt < 4; ++mt)
            acc[g][mt] = (floatx4){0.f, 0.f, 0.f, 0.f};

    // prologue: stages 0,1 in flight (6 outstanding/wave)
    ISSUE(0);
    ISSUE(1);

    // 64 K-steps; ITER(kt) computes stage kt%3, issues kt+2 -> (kt+2)%3.
    for (int t = 0; t < 20; ++t) {
        ITER(0, 2); ITER(1, 0); ITER(2, 1);     // kt = 3t, 3t+1, 3t+2
    }
    ITER(0, 2);                                 // kt = 60
    ITER(1, 0);                                 // kt = 61 (issues loads(63))
    WAITB(3); COMPUTE(2);                       // kt = 62
    WAITB(0); COMPUTE(0);                       // kt = 63

    // ------------------------------------------------------------------ epi
    // All 4 gates wave-local.  C/D: col = lane&15, row = (lane>>4)*4 + reg
    const int lrc   = lane & 15;
    const int lquad = lane >> 4;
    const int colg  = bn0 + wcg * 16 + lrc;
    const int wrow  = wM * 64;
    float* out_ct = out;
    float* out_ht = out + (size_t)M_DIM * H_DIM;

    const float bf_ = bxf[colg] + bhf[colg];
    const float bi_ = bxi[colg] + bhi[colg];
    const float bo_ = bxo[colg] + bho[colg];
    const float bc_ = bxc[colg] + bhc[colg];

#pragma unroll
    for (int mt = 0; mt < 4; ++mt) {
#pragma unroll
        for (int r = 0; r < 4; ++r) {
            const int row = bm0 + wrow + mt * 16 + lquad * 4 + r;
            const float f    = fast_sigmoid(acc[0][mt][r] + bf_);
            const float ii   = fast_sigmoid(acc[1][mt][r] + bi_);
            const float o    = fast_sigmoid(acc[2][mt][r] + bo_);
            const float ctil = fast_tanh(acc[3][mt][r] + bc_);
            const float cv   = c[(size_t)row * H_DIM + colg];
            const float ctn  = f * cv + ctil * ii;
            const float htn  = fast_tanh(ctn) * o;
            out_ct[(size_t)row * H_DIM + colg] = ctn;
            out_ht[(size_t)row * H_DIM + colg] = htn;
        }
    }
}

extern "C" void kernel_launch(void* const* d_in, const int* in_sizes, int n_in,
                              void* d_out, int out_size, void* d_ws, size_t ws_size,
                              hipStream_t stream) {
    (void)in_sizes; (void)n_in; (void)out_size; (void)ws_size;
    const float* x   = (const float*)d_in[0];
    const float* c   = (const float*)d_in[1];
    const float* h   = (const float*)d_in[2];
    const float* Wxf = (const float*)d_in[3];  const float* bxf = (const float*)d_in[4];
    const float* Whf = (const float*)d_in[5];  const float* bhf = (const float*)d_in[6];
    const float* Wxi = (const float*)d_in[7];  const float* bxi = (const float*)d_in[8];
    const float* Whi = (const float*)d_in[9];  const float* bhi = (const float*)d_in[10];
    const float* Wxo = (const float*)d_in[11]; const float* bxo = (const float*)d_in[12];
    const float* Who = (const float*)d_in[13]; const float* bho = (const float*)d_in[14];
    const float* Wxc = (const float*)d_in[15]; const float* bxc = (const float*)d_in[16];
    const float* Whc = (const float*)d_in[17]; const float* bhc = (const float*)d_in[18];
    float* out = (float*)d_out;
    unsigned short* ws = (unsigned short*)d_ws;   // 32768 chunks x 1 KB = 32 MB

    pack_bf16<<<8192, 256, 0, stream>>>(x, h,
        Wxf, Wxi, Wxo, Wxc, Whf, Whi, Who, Whc, ws);

    lstm_fused_kernel<<<512, 512, 0, stream>>>(ws, c,
        bxf, bhf, bxi, bhi, bxo, bho, bxc, bhc, out);
}